// Round 1
// baseline (65.909 us; speedup 1.0000x reference)
//
#include <hip/hip_runtime.h>
#include <math.h>

// SSIM 1D loss: B=16, C=32, T=48000, window=11, sigma=1.5, zero padding.
constexpr int T      = 48000;
constexpr int TILE   = 2048;        // outputs per block
constexpr int TPB    = 256;         // threads per block
constexpr int OPT    = 8;           // outputs per thread (TILE = TPB*OPT)
constexpr int TPR    = (T + TILE - 1) / TILE;  // 24 tiles per row
constexpr int HALO   = 8;           // staging starts at tile_start-8 (need -5; 8 keeps float4 alignment)
constexpr int SSPAN  = TILE + 2 * HALO;        // 2064 staged floats
constexpr int NF4    = SSPAN / 4;              // 516 float4 loads
constexpr float C1f  = 0.0001f;     // 0.01^2
constexpr float C2f  = 0.0009f;     // 0.03^2

// LDS pad: +1 float every 8 -> per-lane stride 9 (coprime with 32 banks) => conflict-free
constexpr int pidx(int j) { return j + (j >> 3); }
constexpr int SLDS = pidx(SSPAN - 1) + 2;

struct W11 { float w[11]; };

__global__ __launch_bounds__(TPB) void ssim_main(
    const float* __restrict__ pred, const float* __restrict__ targ,
    float* __restrict__ partial, W11 wts)
{
    __shared__ float sp[SLDS];
    __shared__ float st[SLDS];
    __shared__ float wsum[TPB / 64];

    const int row  = blockIdx.x / TPR;
    const int tile = blockIdx.x % TPR;
    const int ts   = tile * TILE;
    const float* pr = pred + (size_t)row * T;
    const float* tr = targ + (size_t)row * T;

    // ---- stage tile + halo to LDS (zero-fill OOB == lax zero padding) ----
    for (int k = threadIdx.x; k < NF4; k += TPB) {
        const int g4 = ts - HALO + 4 * k;           // multiple of 4 -> 16B aligned
        float4 a = {0.f, 0.f, 0.f, 0.f}, b = {0.f, 0.f, 0.f, 0.f};
        if (g4 >= 0 && g4 < T) {                    // whole float4 in/out (T%4==0)
            a = *reinterpret_cast<const float4*>(pr + g4);
            b = *reinterpret_cast<const float4*>(tr + g4);
        }
        const int p0 = pidx(4 * k);                 // 4-group never crosses pad boundary
        sp[p0 + 0] = a.x; sp[p0 + 1] = a.y; sp[p0 + 2] = a.z; sp[p0 + 3] = a.w;
        st[p0 + 0] = b.x; st[p0 + 1] = b.y; st[p0 + 2] = b.z; st[p0 + 3] = b.w;
    }
    __syncthreads();

    // ---- per-thread sliding window: 18 staged values cover 8 outputs ----
    const int j0 = threadIdx.x * OPT;               // tile-relative first output
    float P[OPT + 10], Q[OPT + 10];
    #pragma unroll
    for (int k = 0; k < OPT + 10; k++) {
        const int pj = pidx(j0 + 3 + k);            // output j needs staged [j+3, j+13]
        P[k] = sp[pj];
        Q[k] = st[pj];
    }
    float PP[OPT + 10], QQ[OPT + 10], PQ[OPT + 10];
    #pragma unroll
    for (int k = 0; k < OPT + 10; k++) {
        PP[k] = P[k] * P[k];
        QQ[k] = Q[k] * Q[k];
        PQ[k] = P[k] * Q[k];
    }

    float loss = 0.f;
    #pragma unroll
    for (int m = 0; m < OPT; m++) {
        float s1 = 0.f, s2 = 0.f, s11 = 0.f, s22 = 0.f, s12 = 0.f;
        #pragma unroll
        for (int k = 0; k < 11; k++) {
            const float wk = wts.w[k];              // SGPR-resident
            s1  = fmaf(wk, P[m + k],  s1);
            s2  = fmaf(wk, Q[m + k],  s2);
            s11 = fmaf(wk, PP[m + k], s11);
            s22 = fmaf(wk, QQ[m + k], s22);
            s12 = fmaf(wk, PQ[m + k], s12);
        }
        if (ts + j0 + m < T) {                      // tail-tile guard
            const float mu1s = s1 * s1, mu2s = s2 * s2, mu12 = s1 * s2;
            const float sg1 = s11 - mu1s, sg2 = s22 - mu2s, sg12 = s12 - mu12;
            const float num = (2.f * mu12 + C1f) * (2.f * sg12 + C2f);
            const float den = (mu1s + mu2s + C1f) * (sg1 + sg2 + C2f);
            loss += 1.f - num * __builtin_amdgcn_rcpf(den);  // den >= C1*C2 > 0
        }
    }

    // ---- block reduction -> one partial per block ----
    #pragma unroll
    for (int off = 32; off; off >>= 1) loss += __shfl_down(loss, off);
    if ((threadIdx.x & 63) == 0) wsum[threadIdx.x >> 6] = loss;
    __syncthreads();
    if (threadIdx.x == 0) {
        float s = 0.f;
        #pragma unroll
        for (int i = 0; i < TPB / 64; i++) s += wsum[i];
        partial[blockIdx.x] = s;
    }
}

__global__ __launch_bounds__(TPB) void ssim_reduce(
    const float* __restrict__ partial, int n, float* __restrict__ out, float inv_n)
{
    float s = 0.f;
    for (int i = threadIdx.x; i < n; i += TPB) s += partial[i];
    #pragma unroll
    for (int off = 32; off; off >>= 1) s += __shfl_down(s, off);
    __shared__ float ws[TPB / 64];
    if ((threadIdx.x & 63) == 0) ws[threadIdx.x >> 6] = s;
    __syncthreads();
    if (threadIdx.x == 0) {
        float t = 0.f;
        #pragma unroll
        for (int i = 0; i < TPB / 64; i++) t += ws[i];
        out[0] = t * inv_n;
    }
}

extern "C" void kernel_launch(void* const* d_in, const int* in_sizes, int n_in,
                              void* d_out, int out_size, void* d_ws, size_t ws_size,
                              hipStream_t stream)
{
    const float* pred = (const float*)d_in[0];
    const float* targ = (const float*)d_in[1];
    float* out = (float*)d_out;
    float* partial = (float*)d_ws;

    const int n    = in_sizes[0];       // B*C*T = 24,576,000
    const int rows = n / T;             // 512
    const int blocks = rows * TPR;      // 12,288  (needs 48KB of d_ws)

    // Gaussian window computed on host in double (matches numpy), cast to f32.
    W11 wts;
    double g[11], s = 0.0;
    for (int i = 0; i < 11; i++) { g[i] = exp(-((i - 5) * (i - 5)) / 4.5); s += g[i]; }
    for (int i = 0; i < 11; i++) wts.w[i] = (float)(g[i] / s);

    hipLaunchKernelGGL(ssim_main, dim3(blocks), dim3(TPB), 0, stream,
                       pred, targ, partial, wts);
    hipLaunchKernelGGL(ssim_reduce, dim3(1), dim3(TPB), 0, stream,
                       partial, blocks, out, 1.0f / (float)n);
}

// Round 2
// 61.077 us; speedup vs baseline: 1.0791x; 1.0791x over previous
//
#include <hip/hip_runtime.h>
#include <math.h>

// SSIM 1D loss: B=16, C=32, T=48000, window=11, sigma=1.5, zero padding.
// u/v reformulation: u=p+t, v=p-t =>
//   conv(u)=s1+s2, conv(v)=s1-s2, conv(u^2)=s11+2*s12+s22, conv(v^2)=s11-2*s12+s22
// => 4 depthwise convs instead of 5, 2 products/elem instead of 3.
constexpr int T     = 48000;
constexpr int TPB   = 192;            // 3 waves
constexpr int OPT   = 5;              // outputs per thread (odd => stride-5 LDS reads, 2 lanes/bank = free)
constexpr int TILE  = TPB * OPT;      // 960
constexpr int TPR   = T / TILE;       // 50 -- exact, no tail
constexpr int HALO  = 8;              // need 5; 8 keeps float4 alignment
constexpr int SSPAN = TILE + 2 * HALO; // 976
constexpr int NF4   = SSPAN / 4;      // 244
constexpr float C1f = 0.0001f;        // 0.01^2
constexpr float C2f = 0.0009f;        // 0.03^2

struct W11 { float w[11]; };

__global__ __launch_bounds__(TPB) void ssim_main(
    const float* __restrict__ pred, const float* __restrict__ targ,
    float* __restrict__ partial, W11 wts)
{
    __shared__ __align__(16) float su[SSPAN];
    __shared__ __align__(16) float sv[SSPAN];
    __shared__ float wsum[TPB / 64];

    const int row  = blockIdx.x / TPR;
    const int tile = blockIdx.x % TPR;
    const int ts   = tile * TILE;
    const float* pr = pred + (size_t)row * T;
    const float* tr = targ + (size_t)row * T;

    // ---- stage u,v tile + halo to LDS (zero-fill OOB == lax zero padding) ----
    for (int k = threadIdx.x; k < NF4; k += TPB) {
        const int g4 = ts - HALO + 4 * k;            // multiple of 4 -> 16B aligned
        float4 a = {0.f, 0.f, 0.f, 0.f}, b = {0.f, 0.f, 0.f, 0.f};
        if (g4 >= 0 && g4 < T) {                     // whole quad in/out (T%4==0)
            a = *reinterpret_cast<const float4*>(pr + g4);
            b = *reinterpret_cast<const float4*>(tr + g4);
        }
        float4 u, v;
        u.x = a.x + b.x; u.y = a.y + b.y; u.z = a.z + b.z; u.w = a.w + b.w;
        v.x = a.x - b.x; v.y = a.y - b.y; v.z = a.z - b.z; v.w = a.w - b.w;
        *reinterpret_cast<float4*>(su + 4 * k) = u;
        *reinterpret_cast<float4*>(sv + 4 * k) = v;
    }
    __syncthreads();

    // ---- per-thread sliding window: 15 staged values cover 5 outputs ----
    // staged s[i] = x[ts - HALO + i]; output j needs s[j+3 .. j+13]
    const int base = OPT * threadIdx.x + (HALO - 5);  // = 5*tid + 3
    float u[OPT + 10], v[OPT + 10];
    #pragma unroll
    for (int k = 0; k < OPT + 10; k++) { u[k] = su[base + k]; v[k] = sv[base + k]; }
    float uu[OPT + 10], vv[OPT + 10];
    #pragma unroll
    for (int k = 0; k < OPT + 10; k++) { uu[k] = u[k] * u[k]; vv[k] = v[k] * v[k]; }

    float ca[OPT] = {}, cb[OPT] = {}, cc[OPT] = {}, cd[OPT] = {};
    #pragma unroll
    for (int k = 0; k < 11; k++) {
        const float wk = wts.w[k];                    // SGPR-resident
        #pragma unroll
        for (int m = 0; m < OPT; m++) {
            ca[m] = fmaf(wk, u[m + k],  ca[m]);       // s1+s2
            cb[m] = fmaf(wk, v[m + k],  cb[m]);       // s1-s2
            cc[m] = fmaf(wk, uu[m + k], cc[m]);       // s11+2s12+s22
            cd[m] = fmaf(wk, vv[m + k], cd[m]);       // s11-2s12+s22
        }
    }

    float loss = 0.f;
    #pragma unroll
    for (int m = 0; m < OPT; m++) {
        const float aa = ca[m] * ca[m], bb = cb[m] * cb[m];
        const float e  = 0.5f * (aa - bb);            // 2*mu1*mu2
        const float f  = 0.5f * (aa + bb);            // mu1^2 + mu2^2
        const float t2 = 0.5f * (cc[m] - cd[m]);      // 2*s12
        const float sP = 0.5f * (cc[m] + cd[m]);      // s11 + s22
        const float num = (e + C1f) * (t2 - e + C2f); // (2mu12+C1)(2sig12+C2)
        const float den = (f + C1f) * (sP - f + C2f); // (mu1^2+mu2^2+C1)(sig1+sig2+C2)
        loss += 1.f - num * __builtin_amdgcn_rcpf(den);  // den >= C1*C2 > 0
    }

    // ---- block reduction -> one partial per block ----
    #pragma unroll
    for (int off = 32; off; off >>= 1) loss += __shfl_down(loss, off);
    if ((threadIdx.x & 63) == 0) wsum[threadIdx.x >> 6] = loss;
    __syncthreads();
    if (threadIdx.x == 0) {
        float s = 0.f;
        #pragma unroll
        for (int i = 0; i < TPB / 64; i++) s += wsum[i];
        partial[blockIdx.x] = s;
    }
}

__global__ __launch_bounds__(256) void ssim_reduce(
    const float4* __restrict__ partial4, int n4, float* __restrict__ out, float inv_n)
{
    float s = 0.f;
    for (int i = threadIdx.x; i < n4; i += 256) {
        const float4 p = partial4[i];
        s += (p.x + p.y) + (p.z + p.w);
    }
    #pragma unroll
    for (int off = 32; off; off >>= 1) s += __shfl_down(s, off);
    __shared__ float ws[4];
    if ((threadIdx.x & 63) == 0) ws[threadIdx.x >> 6] = s;
    __syncthreads();
    if (threadIdx.x == 0) {
        float t = 0.f;
        #pragma unroll
        for (int i = 0; i < 4; i++) t += ws[i];
        out[0] = t * inv_n;
    }
}

extern "C" void kernel_launch(void* const* d_in, const int* in_sizes, int n_in,
                              void* d_out, int out_size, void* d_ws, size_t ws_size,
                              hipStream_t stream)
{
    const float* pred = (const float*)d_in[0];
    const float* targ = (const float*)d_in[1];
    float* out = (float*)d_out;
    float* partial = (float*)d_ws;

    const int n      = in_sizes[0];     // B*C*T = 24,576,000
    const int rows   = n / T;           // 512
    const int blocks = rows * TPR;      // 25,600 (needs 100 KB of d_ws)

    // Gaussian window computed on host in double (matches numpy), cast to f32.
    W11 wts;
    double g[11], s = 0.0;
    for (int i = 0; i < 11; i++) { g[i] = exp(-((i - 5) * (i - 5)) / 4.5); s += g[i]; }
    for (int i = 0; i < 11; i++) wts.w[i] = (float)(g[i] / s);

    hipLaunchKernelGGL(ssim_main, dim3(blocks), dim3(TPB), 0, stream,
                       pred, targ, partial, wts);
    hipLaunchKernelGGL(ssim_reduce, dim3(1), dim3(256), 0, stream,
                       (const float4*)partial, blocks / 4, out, 1.0f / (float)n);
}